// Round 1
// baseline (840.038 us; speedup 1.0000x reference)
//
#include <hip/hip_runtime.h>

typedef _Float16 f16;
typedef _Float16 f16x4 __attribute__((ext_vector_type(4)));
typedef _Float16 f16x8 __attribute__((ext_vector_type(8)));
typedef float f32x4 __attribute__((ext_vector_type(4)));

#define EMB 1024
#define SEQL 4096
#define BATCH 4
#define NH 16
#define HD 64
#define BH 64           // BATCH*NH
#define MROWS 16384     // BATCH*SEQL

// ---------------- fp32 -> fp16 convert ----------------
__global__ void cvt_kernel(const float* __restrict__ in, f16* __restrict__ out, int n4) {
    int i = blockIdx.x * blockDim.x + threadIdx.x;
    if (i < n4) {
        float4 v = ((const float4*)in)[i];
        f16x4 o = { (f16)v.x, (f16)v.y, (f16)v.z, (f16)v.w };
        ((f16x4*)out)[i] = o;
    }
}

// ---------------- generic MFMA GEMM: C[m][n] = act( sum_k A[m][k]*Bt[n][k] ) ----------------
// MODE 0: fp32 out, plain row-major (row*N+col)          [final Wo GEMM]
// MODE 1: f16 out, (b,h,l,hd) layout; rows are r=b*L+l, cols are e=h*64+hd   [q,u]
// MODE 2: f16 out, (b,h,hd,l) layout; rows are e, cols are r=b*L+l           [kT,vT]
// ACT  0: identity   1: relu(x)*0.125   2: silu
template<int MODE, int ACT>
__global__ __launch_bounds__(256) void gemm_kernel(
    const f16* __restrict__ A, const f16* __restrict__ Bt,
    void* __restrict__ Cv, int M, int N, int K)
{
    const int lane = threadIdx.x & 63;
    const int w    = threadIdx.x >> 6;
    const int rw   = lane & 15;
    const int quad = lane >> 4;
    const int m0 = blockIdx.y * 128 + (w >> 1) * 64;
    const int n0 = blockIdx.x * 128 + (w & 1) * 64;

    f32x4 acc[4][4] = {};
    const f16* Ap = A  + (size_t)(m0 + rw) * K + quad * 8;
    const f16* Bp = Bt + (size_t)(n0 + rw) * K + quad * 8;

    for (int k0 = 0; k0 < K; k0 += 32) {
        f16x8 af[4], bf[4];
        #pragma unroll
        for (int i = 0; i < 4; i++) af[i] = *(const f16x8*)(Ap + (size_t)16 * i * K + k0);
        #pragma unroll
        for (int j = 0; j < 4; j++) bf[j] = *(const f16x8*)(Bp + (size_t)16 * j * K + k0);
        #pragma unroll
        for (int i = 0; i < 4; i++)
            #pragma unroll
            for (int j = 0; j < 4; j++)
                acc[i][j] = __builtin_amdgcn_mfma_f32_16x16x32_f16(af[i], bf[j], acc[i][j], 0, 0, 0);
    }

    #pragma unroll
    for (int i = 0; i < 4; i++) {
        #pragma unroll
        for (int j = 0; j < 4; j++) {
            #pragma unroll
            for (int r = 0; r < 4; r++) {
                int row = m0 + 16 * i + quad * 4 + r;
                int col = n0 + 16 * j + rw;
                float v = acc[i][j][r];
                if (ACT == 1) v = fmaxf(v, 0.0f) * 0.125f;
                if (ACT == 2) v = v / (1.0f + __expf(-v));
                if (MODE == 0) {
                    ((float*)Cv)[(size_t)row * N + col] = v;
                } else if (MODE == 1) {
                    int b = row >> 12, l = row & 4095, h = col >> 6, hd = col & 63;
                    ((f16*)Cv)[(((size_t)(b * 16 + h) * 4096 + l) << 6) + hd] = (f16)v;
                } else {
                    int b = col >> 12, l = col & 4095;
                    ((f16*)Cv)[(((size_t)b * 1024 + row) << 12) + l] = (f16)v;
                }
            }
        }
    }
}

// ---------------- kv[m][n] = sum_l k[l][m] * v[l][n], per (b,h) ----------------
// kT, vT layout (b,h,hd,l) -> both operands contiguous in l
__global__ __launch_bounds__(256) void kv_kernel(
    const f16* __restrict__ kT, const f16* __restrict__ vT, f16* __restrict__ kvg)
{
    const int bh   = blockIdx.x;
    const int lane = threadIdx.x & 63;
    const int w    = threadIdx.x >> 6;
    const int rw   = lane & 15;
    const int quad = lane >> 4;

    const f16* kp = kT + (size_t)bh * HD * SEQL + (size_t)(w * 16 + rw) * SEQL + quad * 8;
    const f16* vp = vT + (size_t)bh * HD * SEQL + (size_t)rw * SEQL + quad * 8;

    f32x4 acc[4] = {};
    for (int k0 = 0; k0 < SEQL; k0 += 32) {
        f16x8 a = *(const f16x8*)(kp + k0);
        #pragma unroll
        for (int t = 0; t < 4; t++) {
            f16x8 b = *(const f16x8*)(vp + (size_t)16 * t * SEQL + k0);
            acc[t] = __builtin_amdgcn_mfma_f32_16x16x32_f16(a, b, acc[t], 0, 0, 0);
        }
    }
    f16* out = kvg + (size_t)bh * HD * HD;
    #pragma unroll
    for (int t = 0; t < 4; t++)
        #pragma unroll
        for (int r = 0; r < 4; r++)
            out[(w * 16 + quad * 4 + r) * 64 + t * 16 + rw] = (f16)acc[t][r];
}

// ---------------- out = SRMSNorm(q @ kv) * u, written to (b,l,emb) f16 ----------------
__global__ __launch_bounds__(256) void ret_out_kernel(
    const f16* __restrict__ q, const f16* __restrict__ u,
    const f16* __restrict__ kvg, f16* __restrict__ o)
{
    const int bh    = blockIdx.x;
    const int chunk = blockIdx.y;
    const int lane  = threadIdx.x & 63;
    const int w     = threadIdx.x >> 6;
    const int rw    = lane & 15;
    const int quad  = lane >> 4;

    // kv fragments (loop-invariant): B[k][n] with k = s*32+quad*8+j, n = t*16+rw
    const f16* kvp = kvg + (size_t)bh * 4096;
    f16x8 bf[2][4];
    #pragma unroll
    for (int s = 0; s < 2; s++)
        #pragma unroll
        for (int t = 0; t < 4; t++)
            #pragma unroll
            for (int j = 0; j < 8; j++)
                bf[s][t][j] = kvp[(s * 32 + quad * 8 + j) * 64 + t * 16 + rw];

    const f16* qp = q + (size_t)bh * SEQL * HD;
    const f16* up = u + (size_t)bh * SEQL * HD;
    const int b = bh >> 4, h = bh & 15;
    f16* op = o + (size_t)b * SEQL * EMB + h * 64;

    const int l_wave = chunk * 512 + w * 128;
    for (int s = 0; s < 8; s++) {
        const int l0 = l_wave + s * 16;
        f16x8 a0 = *(const f16x8*)(qp + (size_t)(l0 + rw) * 64 + quad * 8);
        f16x8 a1 = *(const f16x8*)(qp + (size_t)(l0 + rw) * 64 + 32 + quad * 8);
        f32x4 acc[4] = {};
        #pragma unroll
        for (int t = 0; t < 4; t++) {
            acc[t] = __builtin_amdgcn_mfma_f32_16x16x32_f16(a0, bf[0][t], acc[t], 0, 0, 0);
            acc[t] = __builtin_amdgcn_mfma_f32_16x16x32_f16(a1, bf[1][t], acc[t], 0, 0, 0);
        }
        // SRMSNorm over the 64 cols of each row; row = l0+quad*4+r, lane holds cols {rw,rw+16,rw+32,rw+48}
        float inv[4];
        #pragma unroll
        for (int r = 0; r < 4; r++) {
            float ss = acc[0][r] * acc[0][r] + acc[1][r] * acc[1][r]
                     + acc[2][r] * acc[2][r] + acc[3][r] * acc[3][r];
            #pragma unroll
            for (int msk = 1; msk < 16; msk <<= 1)
                ss += __shfl_xor(ss, msk, 16);
            // n = sqrt(ss)/8 ; out = x / max(n,1e-12) = x * 8/max(sqrt(ss), 8e-12)
            inv[r] = 8.0f / fmaxf(sqrtf(ss), 8e-12f);
        }
        #pragma unroll
        for (int t = 0; t < 4; t++)
            #pragma unroll
            for (int r = 0; r < 4; r++) {
                int l = l0 + quad * 4 + r;
                int col = t * 16 + rw;
                float uval = (float)up[(size_t)l * 64 + col];
                op[(size_t)l * EMB + col] = (f16)(acc[t][r] * inv[r] * uval);
            }
    }
}

extern "C" void kernel_launch(void* const* d_in, const int* in_sizes, int n_in,
                              void* d_out, int out_size, void* d_ws, size_t ws_size,
                              hipStream_t stream)
{
    const float* x  = (const float*)d_in[0];
    const float* Wsrc[5] = { (const float*)d_in[1], (const float*)d_in[2],
                             (const float*)d_in[3], (const float*)d_in[4],
                             (const float*)d_in[5] };   // Wq, Wk, Wv, Wu, Wo

    char* ws = (char*)d_ws;
    size_t off = 0;
    f16* x16 = (f16*)(ws + off); off += (size_t)MROWS * EMB * 2;
    f16* w16[5];
    for (int i = 0; i < 5; i++) { w16[i] = (f16*)(ws + off); off += (size_t)EMB * EMB * 2; }
    f16* qb  = (f16*)(ws + off); off += (size_t)MROWS * EMB * 2;
    f16* kTb = (f16*)(ws + off); off += (size_t)MROWS * EMB * 2;
    f16* vTb = (f16*)(ws + off); off += (size_t)MROWS * EMB * 2;
    f16* ub  = (f16*)(ws + off); off += (size_t)MROWS * EMB * 2;
    f16* kvb = (f16*)(ws + off); off += (size_t)BH * HD * HD * 2;
    f16* ob  = x16;  // reuse: x16 dead after the 4 projection GEMMs

    // converts
    cvt_kernel<<<(MROWS * EMB / 4) / 256, 256, 0, stream>>>(x, x16, MROWS * EMB / 4);
    for (int i = 0; i < 5; i++)
        cvt_kernel<<<(EMB * EMB / 4) / 256, 256, 0, stream>>>(Wsrc[i], w16[i], EMB * EMB / 4);

    dim3 blk(256);
    // q = relu(x Wq^T)/8   -> (b,h,l,hd)
    gemm_kernel<1, 1><<<dim3(8, 128), blk, 0, stream>>>(x16, w16[0], qb, MROWS, EMB, EMB);
    // u = silu(x Wu^T)     -> (b,h,l,hd)
    gemm_kernel<1, 2><<<dim3(8, 128), blk, 0, stream>>>(x16, w16[3], ub, MROWS, EMB, EMB);
    // kT = relu(Wk x^T)/8  -> (b,h,hd,l)
    gemm_kernel<2, 1><<<dim3(128, 8), blk, 0, stream>>>(w16[1], x16, kTb, EMB, MROWS, EMB);
    // vT = Wv x^T          -> (b,h,hd,l)
    gemm_kernel<2, 0><<<dim3(128, 8), blk, 0, stream>>>(w16[2], x16, vTb, EMB, MROWS, EMB);

    // retention core
    kv_kernel<<<dim3(BH), blk, 0, stream>>>(kTb, vTb, kvb);
    ret_out_kernel<<<dim3(BH, 8), blk, 0, stream>>>(qb, ub, kvb, ob);

    // final: out = o @ Wo^T, fp32
    gemm_kernel<0, 0><<<dim3(8, 128), blk, 0, stream>>>(ob, w16[4], d_out, MROWS, EMB, EMB);
}

// Round 2
// 514.287 us; speedup vs baseline: 1.6334x; 1.6334x over previous
//
#include <hip/hip_runtime.h>

typedef _Float16 f16;
typedef _Float16 f16x4 __attribute__((ext_vector_type(4)));
typedef _Float16 f16x8 __attribute__((ext_vector_type(8)));
typedef float f32x4 __attribute__((ext_vector_type(4)));

#define EMB 1024
#define SEQL 4096
#define BATCH 4
#define NH 16
#define HD 64
#define BH 64           // BATCH*NH
#define MROWS 16384     // BATCH*SEQL

#define GLOAD_LDS(gp, lp) \
    __builtin_amdgcn_global_load_lds((const __attribute__((address_space(1))) void*)(gp), \
                                     (__attribute__((address_space(3))) void*)(lp), 16, 0, 0)

// ---------------- fp32 -> fp16 convert ----------------
__global__ void cvt_kernel(const float* __restrict__ in, f16* __restrict__ out, int n4) {
    int i = blockIdx.x * blockDim.x + threadIdx.x;
    if (i < n4) {
        float4 v = ((const float4*)in)[i];
        f16x4 o = { (f16)v.x, (f16)v.y, (f16)v.z, (f16)v.w };
        ((f16x4*)out)[i] = o;
    }
}

struct WPtrs { const float* p[5]; };

// all five 1024x1024 weights in one launch; dst are contiguous in ws
__global__ void cvt_w_kernel(WPtrs wp, f16* __restrict__ out) {
    int i = blockIdx.x * blockDim.x + threadIdx.x;   // element-group within one weight
    int wsel = blockIdx.y;
    const float4* src = (const float4*)wp.p[wsel];
    float4 v = src[i];
    f16x4 o = { (f16)v.x, (f16)v.y, (f16)v.z, (f16)v.w };
    ((f16x4*)(out + (size_t)wsel * EMB * EMB))[i] = o;
}

// ---------------- m97-style MFMA GEMM: C[m][n] = act( sum_k A[m][k]*Bt[n][k] ) ----------------
// 128x128 block tile, BK=32, LDS staging via global_load_lds width-16, 4 waves x 64x64.
// MODE 0: fp32 out, plain row-major (row*N+col)          [final Wo GEMM]
// MODE 1: f16 out, (b,h,l,hd) layout; rows are r=b*L+l, cols are e=h*64+hd   [q,u]
// MODE 2: f16 out, (b,h,hd,l) layout; rows are e, cols are r=b*L+l           [kT,vT]
// ACT  0: identity   1: relu(x)*0.125   2: silu
template<int MODE, int ACT>
__global__ __launch_bounds__(256) void gemm_kernel(
    const f16* __restrict__ A, const f16* __restrict__ Bt,
    void* __restrict__ Cv, int M, int N, int K)
{
    __shared__ f16 As[128 * 32];
    __shared__ f16 Bs[128 * 32];

    const int lane = threadIdx.x & 63;
    const int w    = threadIdx.x >> 6;
    const int rw   = lane & 15;
    const int quad = lane >> 4;
    const int m0 = blockIdx.y * 128;
    const int n0 = blockIdx.x * 128;
    const int mw = (w >> 1) * 64;     // wave's m offset within tile
    const int nw = (w & 1) * 64;      // wave's n offset within tile

    // staging: each wave stages 2x16 rows of A and of B per K-step.
    // lane i -> row srow=i>>2, col (i&3)*8 ; LDS linear offset = i*8 f16 = i*16 B (HW: base+lane*16)
    const int srow = lane >> 2;
    const int scol = (lane & 3) * 8;
    const f16* ag0 = A  + (size_t)(m0 + w * 16 + srow) * K + scol;
    const f16* ag1 = A  + (size_t)(m0 + 64 + w * 16 + srow) * K + scol;
    const f16* bg0 = Bt + (size_t)(n0 + w * 16 + srow) * K + scol;
    const f16* bg1 = Bt + (size_t)(n0 + 64 + w * 16 + srow) * K + scol;
    f16* la0 = &As[(w * 16) * 32];
    f16* la1 = &As[(64 + w * 16) * 32];
    f16* lb0 = &Bs[(w * 16) * 32];
    f16* lb1 = &Bs[(64 + w * 16) * 32];

    f32x4 acc[4][4] = {};

    for (int k0 = 0; k0 < K; k0 += 32) {
        __syncthreads();
        GLOAD_LDS(ag0 + k0, la0);
        GLOAD_LDS(ag1 + k0, la1);
        GLOAD_LDS(bg0 + k0, lb0);
        GLOAD_LDS(bg1 + k0, lb1);
        __syncthreads();

        f16x8 af[4], bf[4];
        #pragma unroll
        for (int i = 0; i < 4; i++)
            af[i] = *(const f16x8*)&As[(mw + 16 * i + rw) * 32 + quad * 8];
        #pragma unroll
        for (int j = 0; j < 4; j++)
            bf[j] = *(const f16x8*)&Bs[(nw + 16 * j + rw) * 32 + quad * 8];
        #pragma unroll
        for (int i = 0; i < 4; i++)
            #pragma unroll
            for (int j = 0; j < 4; j++)
                acc[i][j] = __builtin_amdgcn_mfma_f32_16x16x32_f16(af[i], bf[j], acc[i][j], 0, 0, 0);
    }

    #pragma unroll
    for (int i = 0; i < 4; i++) {
        #pragma unroll
        for (int j = 0; j < 4; j++) {
            #pragma unroll
            for (int r = 0; r < 4; r++) {
                int row = m0 + mw + 16 * i + quad * 4 + r;
                int col = n0 + nw + 16 * j + rw;
                float v = acc[i][j][r];
                if (ACT == 1) v = fmaxf(v, 0.0f) * 0.125f;
                if (ACT == 2) v = v / (1.0f + __expf(-v));
                if (MODE == 0) {
                    ((float*)Cv)[(size_t)row * N + col] = v;
                } else if (MODE == 1) {
                    int b = row >> 12, l = row & 4095, h = col >> 6, hd = col & 63;
                    ((f16*)Cv)[(((size_t)(b * 16 + h) * 4096 + l) << 6) + hd] = (f16)v;
                } else {
                    int b = col >> 12, l = col & 4095;
                    ((f16*)Cv)[(((size_t)b * 1024 + row) << 12) + l] = (f16)v;
                }
            }
        }
    }
}

// ---------------- kv[m][n] = sum_l k[l][m] * v[l][n], per (b,h) ----------------
// kT, vT layout (b,h,hd,l) -> both operands contiguous in l
__global__ __launch_bounds__(256) void kv_kernel(
    const f16* __restrict__ kT, const f16* __restrict__ vT, f16* __restrict__ kvg)
{
    const int bh   = blockIdx.x;
    const int lane = threadIdx.x & 63;
    const int w    = threadIdx.x >> 6;
    const int rw   = lane & 15;
    const int quad = lane >> 4;

    const f16* kp = kT + (size_t)bh * HD * SEQL + (size_t)(w * 16 + rw) * SEQL + quad * 8;
    const f16* vp = vT + (size_t)bh * HD * SEQL + (size_t)rw * SEQL + quad * 8;

    f32x4 acc[4] = {};
    for (int k0 = 0; k0 < SEQL; k0 += 32) {
        f16x8 a = *(const f16x8*)(kp + k0);
        #pragma unroll
        for (int t = 0; t < 4; t++) {
            f16x8 b = *(const f16x8*)(vp + (size_t)16 * t * SEQL + k0);
            acc[t] = __builtin_amdgcn_mfma_f32_16x16x32_f16(a, b, acc[t], 0, 0, 0);
        }
    }
    f16* out = kvg + (size_t)bh * HD * HD;
    #pragma unroll
    for (int t = 0; t < 4; t++)
        #pragma unroll
        for (int r = 0; r < 4; r++)
            out[(w * 16 + quad * 4 + r) * 64 + t * 16 + rw] = (f16)acc[t][r];
}

// ---------------- out = SRMSNorm(q @ kv) * u, written to (b,l,emb) f16 ----------------
__global__ __launch_bounds__(256) void ret_out_kernel(
    const f16* __restrict__ q, const f16* __restrict__ u,
    const f16* __restrict__ kvg, f16* __restrict__ o)
{
    const int bh    = blockIdx.x;
    const int chunk = blockIdx.y;
    const int lane  = threadIdx.x & 63;
    const int w     = threadIdx.x >> 6;
    const int rw    = lane & 15;
    const int quad  = lane >> 4;

    // kv fragments (loop-invariant): B[k][n] with k = s*32+quad*8+j, n = t*16+rw
    const f16* kvp = kvg + (size_t)bh * 4096;
    f16x8 bf[2][4];
    #pragma unroll
    for (int s = 0; s < 2; s++)
        #pragma unroll
        for (int t = 0; t < 4; t++)
            #pragma unroll
            for (int j = 0; j < 8; j++)
                bf[s][t][j] = kvp[(s * 32 + quad * 8 + j) * 64 + t * 16 + rw];

    const f16* qp = q + (size_t)bh * SEQL * HD;
    const f16* up = u + (size_t)bh * SEQL * HD;
    const int b = bh >> 4, h = bh & 15;
    f16* op = o + (size_t)b * SEQL * EMB + h * 64;

    const int l_wave = chunk * 512 + w * 128;
    for (int s = 0; s < 8; s++) {
        const int l0 = l_wave + s * 16;
        f16x8 a0 = *(const f16x8*)(qp + (size_t)(l0 + rw) * 64 + quad * 8);
        f16x8 a1 = *(const f16x8*)(qp + (size_t)(l0 + rw) * 64 + 32 + quad * 8);
        f32x4 acc[4] = {};
        #pragma unroll
        for (int t = 0; t < 4; t++) {
            acc[t] = __builtin_amdgcn_mfma_f32_16x16x32_f16(a0, bf[0][t], acc[t], 0, 0, 0);
            acc[t] = __builtin_amdgcn_mfma_f32_16x16x32_f16(a1, bf[1][t], acc[t], 0, 0, 0);
        }
        // SRMSNorm over the 64 cols of each row; row = l0+quad*4+r, lane holds cols {rw,rw+16,rw+32,rw+48}
        float inv[4];
        #pragma unroll
        for (int r = 0; r < 4; r++) {
            float ss = acc[0][r] * acc[0][r] + acc[1][r] * acc[1][r]
                     + acc[2][r] * acc[2][r] + acc[3][r] * acc[3][r];
            #pragma unroll
            for (int msk = 1; msk < 16; msk <<= 1)
                ss += __shfl_xor(ss, msk, 16);
            // n = sqrt(ss)/8 ; out = x / max(n,1e-12) = x * 8/max(sqrt(ss), 8e-12)
            inv[r] = 8.0f / fmaxf(sqrtf(ss), 8e-12f);
        }
        #pragma unroll
        for (int t = 0; t < 4; t++)
            #pragma unroll
            for (int r = 0; r < 4; r++) {
                int l = l0 + quad * 4 + r;
                int col = t * 16 + rw;
                float uval = (float)up[(size_t)l * 64 + col];
                op[(size_t)l * EMB + col] = (f16)(acc[t][r] * inv[r] * uval);
            }
    }
}

extern "C" void kernel_launch(void* const* d_in, const int* in_sizes, int n_in,
                              void* d_out, int out_size, void* d_ws, size_t ws_size,
                              hipStream_t stream)
{
    const float* x = (const float*)d_in[0];
    WPtrs wp;
    for (int i = 0; i < 5; i++) wp.p[i] = (const float*)d_in[1 + i];  // Wq, Wk, Wv, Wu, Wo

    char* ws = (char*)d_ws;
    size_t off = 0;
    f16* x16 = (f16*)(ws + off); off += (size_t)MROWS * EMB * 2;
    f16* w16 = (f16*)(ws + off); off += (size_t)5 * EMB * EMB * 2;   // 5 weights, contiguous
    f16* qb  = (f16*)(ws + off); off += (size_t)MROWS * EMB * 2;
    f16* kTb = (f16*)(ws + off); off += (size_t)MROWS * EMB * 2;
    f16* vTb = (f16*)(ws + off); off += (size_t)MROWS * EMB * 2;
    f16* ub  = (f16*)(ws + off); off += (size_t)MROWS * EMB * 2;
    f16* kvb = (f16*)(ws + off); off += (size_t)BH * HD * HD * 2;
    f16* ob  = x16;  // reuse: x16 dead after the 4 projection GEMMs

    // converts
    cvt_kernel<<<(MROWS * EMB / 4) / 256, 256, 0, stream>>>(x, x16, MROWS * EMB / 4);
    cvt_w_kernel<<<dim3((EMB * EMB / 4) / 256, 5), 256, 0, stream>>>(wp, w16);

    f16* Wq = w16;
    f16* Wk = w16 + (size_t)1 * EMB * EMB;
    f16* Wv = w16 + (size_t)2 * EMB * EMB;
    f16* Wu = w16 + (size_t)3 * EMB * EMB;
    f16* Wo = w16 + (size_t)4 * EMB * EMB;

    dim3 blk(256);
    // q = relu(x Wq^T)/8   -> (b,h,l,hd)
    gemm_kernel<1, 1><<<dim3(8, 128), blk, 0, stream>>>(x16, Wq, qb, MROWS, EMB, EMB);
    // u = silu(x Wu^T)     -> (b,h,l,hd)
    gemm_kernel<1, 2><<<dim3(8, 128), blk, 0, stream>>>(x16, Wu, ub, MROWS, EMB, EMB);
    // kT = relu(Wk x^T)/8  -> (b,h,hd,l)
    gemm_kernel<2, 1><<<dim3(128, 8), blk, 0, stream>>>(Wk, x16, kTb, EMB, MROWS, EMB);
    // vT = Wv x^T          -> (b,h,hd,l)
    gemm_kernel<2, 0><<<dim3(128, 8), blk, 0, stream>>>(Wv, x16, vTb, EMB, MROWS, EMB);

    // retention core
    kv_kernel<<<dim3(BH), blk, 0, stream>>>(kTb, vTb, kvb);
    ret_out_kernel<<<dim3(BH, 8), blk, 0, stream>>>(qb, ub, kvb, ob);

    // final: out = o @ Wo^T, fp32
    gemm_kernel<0, 0><<<dim3(8, 128), blk, 0, stream>>>(ob, Wo, d_out, MROWS, EMB, EMB);
}

// Round 3
// 449.703 us; speedup vs baseline: 1.8680x; 1.1436x over previous
//
#include <hip/hip_runtime.h>

typedef _Float16 f16;
typedef _Float16 f16x4 __attribute__((ext_vector_type(4)));
typedef _Float16 f16x8 __attribute__((ext_vector_type(8)));
typedef float f32x4 __attribute__((ext_vector_type(4)));

#define EMB 1024
#define SEQL 4096
#define BATCH 4
#define NH 16
#define HD 64
#define BH 64           // BATCH*NH
#define MROWS 16384     // BATCH*SEQL
#define KVSPLIT 16      // l-chunks for split-K kv

#define GLOAD_LDS(gp, lp) \
    __builtin_amdgcn_global_load_lds((const __attribute__((address_space(1))) void*)(gp), \
                                     (__attribute__((address_space(3))) void*)(lp), 16, 0, 0)

// ---------------- fp32 -> fp16 convert ----------------
__global__ void cvt_kernel(const float* __restrict__ in, f16* __restrict__ out, int n4) {
    int i = blockIdx.x * blockDim.x + threadIdx.x;
    if (i < n4) {
        float4 v = ((const float4*)in)[i];
        f16x4 o = { (f16)v.x, (f16)v.y, (f16)v.z, (f16)v.w };
        ((f16x4*)out)[i] = o;
    }
}

struct WPtrs { const float* p[5]; };

// five 1024x1024 weights in one launch; dst contiguous in ws (order given by wp)
__global__ void cvt_w_kernel(WPtrs wp, f16* __restrict__ out) {
    int i = blockIdx.x * blockDim.x + threadIdx.x;
    int wsel = blockIdx.y;
    const float4* src = (const float4*)wp.p[wsel];
    float4 v = src[i];
    f16x4 o = { (f16)v.x, (f16)v.y, (f16)v.z, (f16)v.w };
    ((f16x4*)(out + (size_t)wsel * EMB * EMB))[i] = o;
}

__global__ void zero_kernel(float4* __restrict__ p, int n4) {
    int i = blockIdx.x * blockDim.x + threadIdx.x;
    if (i < n4) p[i] = float4{0.f, 0.f, 0.f, 0.f};
}

// ---------------- m97-style MFMA GEMM: C[m][n] = act( sum_k A[m][k]*Bt[n][k] ) ----------------
// 128x128 block tile, BK=32, LDS staging via global_load_lds width-16, 4 waves x 64x64.
// MODE 0: fp32 out, plain row-major (row*N+col)                     [final Wo GEMM]
// MODE 3: f16 out, merged q|u: col<1024 -> relu/8 into q (b,h,l,hd); col>=1024 -> silu into u
// MODE 4: f16 out, merged kT|vT: row<1024 -> relu/8 into kT (b,h,hd,l); row>=1024 -> vT plain
template<int MODE>
__global__ __launch_bounds__(256) void gemm_kernel(
    const f16* __restrict__ A, const f16* __restrict__ Bt,
    void* __restrict__ Cv, int M, int N, int K)
{
    __shared__ f16 As[128 * 32];
    __shared__ f16 Bs[128 * 32];

    const int lane = threadIdx.x & 63;
    const int w    = threadIdx.x >> 6;
    const int rw   = lane & 15;
    const int quad = lane >> 4;
    const int m0 = blockIdx.y * 128;
    const int n0 = blockIdx.x * 128;
    const int mw = (w >> 1) * 64;
    const int nw = (w & 1) * 64;

    const int srow = lane >> 2;
    const int scol = (lane & 3) * 8;
    const f16* ag0 = A  + (size_t)(m0 + w * 16 + srow) * K + scol;
    const f16* ag1 = A  + (size_t)(m0 + 64 + w * 16 + srow) * K + scol;
    const f16* bg0 = Bt + (size_t)(n0 + w * 16 + srow) * K + scol;
    const f16* bg1 = Bt + (size_t)(n0 + 64 + w * 16 + srow) * K + scol;
    f16* la0 = &As[(w * 16) * 32];
    f16* la1 = &As[(64 + w * 16) * 32];
    f16* lb0 = &Bs[(w * 16) * 32];
    f16* lb1 = &Bs[(64 + w * 16) * 32];

    f32x4 acc[4][4] = {};

    for (int k0 = 0; k0 < K; k0 += 32) {
        __syncthreads();
        GLOAD_LDS(ag0 + k0, la0);
        GLOAD_LDS(ag1 + k0, la1);
        GLOAD_LDS(bg0 + k0, lb0);
        GLOAD_LDS(bg1 + k0, lb1);
        __syncthreads();

        f16x8 af[4], bf[4];
        #pragma unroll
        for (int i = 0; i < 4; i++)
            af[i] = *(const f16x8*)&As[(mw + 16 * i + rw) * 32 + quad * 8];
        #pragma unroll
        for (int j = 0; j < 4; j++)
            bf[j] = *(const f16x8*)&Bs[(nw + 16 * j + rw) * 32 + quad * 8];
        #pragma unroll
        for (int i = 0; i < 4; i++)
            #pragma unroll
            for (int j = 0; j < 4; j++)
                acc[i][j] = __builtin_amdgcn_mfma_f32_16x16x32_f16(af[i], bf[j], acc[i][j], 0, 0, 0);
    }

    #pragma unroll
    for (int i = 0; i < 4; i++) {
        #pragma unroll
        for (int j = 0; j < 4; j++) {
            #pragma unroll
            for (int r = 0; r < 4; r++) {
                int row = m0 + mw + 16 * i + quad * 4 + r;
                int col = n0 + nw + 16 * j + rw;
                float v = acc[i][j][r];
                if (MODE == 0) {
                    ((float*)Cv)[(size_t)row * N + col] = v;
                } else if (MODE == 3) {
                    int sel = col >> 10, e = col & 1023;
                    float vv = sel ? (v / (1.0f + __expf(-v))) : (fmaxf(v, 0.0f) * 0.125f);
                    int b = row >> 12, l = row & 4095, h = e >> 6, hd = e & 63;
                    ((f16*)Cv)[(size_t)sel * MROWS * EMB +
                               (((size_t)(b * 16 + h) * 4096 + l) << 6) + hd] = (f16)vv;
                } else {
                    int sel = row >> 10, e = row & 1023;
                    float vv = sel ? v : (fmaxf(v, 0.0f) * 0.125f);
                    int b = col >> 12, l = col & 4095;
                    ((f16*)Cv)[(size_t)sel * MROWS * EMB +
                               (((size_t)b * 1024 + e) << 12) + l] = (f16)vv;
                }
            }
        }
    }
}

// ---------------- split-K kv: kv[m][n] += sum_{l in chunk} k[l][m]*v[l][n] ----------------
__global__ __launch_bounds__(256) void kv_split_kernel(
    const f16* __restrict__ kT, const f16* __restrict__ vT, float* __restrict__ kv32)
{
    const int bh    = blockIdx.x;
    const int chunk = blockIdx.y;
    const int lane  = threadIdx.x & 63;
    const int w     = threadIdx.x >> 6;
    const int rw    = lane & 15;
    const int quad  = lane >> 4;
    const int lbase = chunk * (SEQL / KVSPLIT);

    const f16* kp = kT + (size_t)bh * HD * SEQL + (size_t)(w * 16 + rw) * SEQL + lbase + quad * 8;
    const f16* vp = vT + (size_t)bh * HD * SEQL + (size_t)rw * SEQL + lbase + quad * 8;

    f32x4 acc[4] = {};
    for (int k0 = 0; k0 < SEQL / KVSPLIT; k0 += 32) {
        f16x8 a = *(const f16x8*)(kp + k0);
        #pragma unroll
        for (int t = 0; t < 4; t++) {
            f16x8 b = *(const f16x8*)(vp + (size_t)16 * t * SEQL + k0);
            acc[t] = __builtin_amdgcn_mfma_f32_16x16x32_f16(a, b, acc[t], 0, 0, 0);
        }
    }
    float* out = kv32 + (size_t)bh * HD * HD;
    #pragma unroll
    for (int t = 0; t < 4; t++)
        #pragma unroll
        for (int r = 0; r < 4; r++)
            atomicAdd(&out[(w * 16 + quad * 4 + r) * 64 + t * 16 + rw], acc[t][r]);
}

// ---------------- out = SRMSNorm(q @ kv) * u, written to (b,l,emb) f16 ----------------
__global__ __launch_bounds__(256) void ret_out_kernel(
    const f16* __restrict__ q, const f16* __restrict__ u,
    const float* __restrict__ kv32, f16* __restrict__ o)
{
    const int bh    = blockIdx.x;
    const int chunk = blockIdx.y;
    const int lane  = threadIdx.x & 63;
    const int w     = threadIdx.x >> 6;
    const int rw    = lane & 15;
    const int quad  = lane >> 4;

    // kv fragments (loop-invariant): B[k][n] with k = s*32+quad*8+j, n = t*16+rw
    const float* kvp = kv32 + (size_t)bh * 4096;
    f16x8 bf[2][4];
    #pragma unroll
    for (int s = 0; s < 2; s++)
        #pragma unroll
        for (int t = 0; t < 4; t++)
            #pragma unroll
            for (int j = 0; j < 8; j++)
                bf[s][t][j] = (f16)kvp[(s * 32 + quad * 8 + j) * 64 + t * 16 + rw];

    const f16* qp = q + (size_t)bh * SEQL * HD;
    const f16* up = u + (size_t)bh * SEQL * HD;
    const int b = bh >> 4, h = bh & 15;
    f16* op = o + (size_t)b * SEQL * EMB + h * 64;

    const int l_wave = chunk * 512 + w * 128;
    for (int s = 0; s < 8; s++) {
        const int l0 = l_wave + s * 16;
        f16x8 a0 = *(const f16x8*)(qp + (size_t)(l0 + rw) * 64 + quad * 8);
        f16x8 a1 = *(const f16x8*)(qp + (size_t)(l0 + rw) * 64 + 32 + quad * 8);
        f32x4 acc[4] = {};
        #pragma unroll
        for (int t = 0; t < 4; t++) {
            acc[t] = __builtin_amdgcn_mfma_f32_16x16x32_f16(a0, bf[0][t], acc[t], 0, 0, 0);
            acc[t] = __builtin_amdgcn_mfma_f32_16x16x32_f16(a1, bf[1][t], acc[t], 0, 0, 0);
        }
        float inv[4];
        #pragma unroll
        for (int r = 0; r < 4; r++) {
            float ss = acc[0][r] * acc[0][r] + acc[1][r] * acc[1][r]
                     + acc[2][r] * acc[2][r] + acc[3][r] * acc[3][r];
            #pragma unroll
            for (int msk = 1; msk < 16; msk <<= 1)
                ss += __shfl_xor(ss, msk, 16);
            inv[r] = 8.0f / fmaxf(sqrtf(ss), 8e-12f);
        }
        #pragma unroll
        for (int t = 0; t < 4; t++)
            #pragma unroll
            for (int r = 0; r < 4; r++) {
                int l = l0 + quad * 4 + r;
                int col = t * 16 + rw;
                float uval = (float)up[(size_t)l * 64 + col];
                op[(size_t)l * EMB + col] = (f16)(acc[t][r] * inv[r] * uval);
            }
    }
}

extern "C" void kernel_launch(void* const* d_in, const int* in_sizes, int n_in,
                              void* d_out, int out_size, void* d_ws, size_t ws_size,
                              hipStream_t stream)
{
    const float* x = (const float*)d_in[0];
    // dst slot order: Wq, Wu, Wk, Wv, Wo  (so [Wq;Wu] and [Wk;Wv] are contiguous)
    WPtrs wp;
    wp.p[0] = (const float*)d_in[1];  // Wq
    wp.p[1] = (const float*)d_in[4];  // Wu
    wp.p[2] = (const float*)d_in[2];  // Wk
    wp.p[3] = (const float*)d_in[3];  // Wv
    wp.p[4] = (const float*)d_in[5];  // Wo

    char* ws = (char*)d_ws;
    size_t off = 0;
    f16* x16 = (f16*)(ws + off); off += (size_t)MROWS * EMB * 2;
    f16* w16 = (f16*)(ws + off); off += (size_t)5 * EMB * EMB * 2;
    f16* qb  = (f16*)(ws + off); off += (size_t)MROWS * EMB * 2;   // q
    f16* ub  = (f16*)(ws + off); off += (size_t)MROWS * EMB * 2;   // u (contiguous after q)
    f16* kTb = (f16*)(ws + off); off += (size_t)MROWS * EMB * 2;   // kT
    f16* vTb = (f16*)(ws + off); off += (size_t)MROWS * EMB * 2;   // vT (contiguous after kT)
    float* kv32 = (float*)(ws + off); off += (size_t)BH * HD * HD * 4;
    f16* ob  = x16;  // reuse: x16 dead after the two merged projection GEMMs
    (void)ub; (void)vTb;

    // converts + kv zero-init
    cvt_kernel<<<(MROWS * EMB / 4) / 256, 256, 0, stream>>>(x, x16, MROWS * EMB / 4);
    cvt_w_kernel<<<dim3((EMB * EMB / 4) / 256, 5), 256, 0, stream>>>(wp, w16);
    zero_kernel<<<(BH * HD * HD / 4 + 255) / 256, 256, 0, stream>>>((float4*)kv32, BH * HD * HD / 4);

    f16* Wqu = w16;                              // [Wq; Wu]  2048 x 1024
    f16* Wkv = w16 + (size_t)2 * EMB * EMB;      // [Wk; Wv]  2048 x 1024
    f16* Wo  = w16 + (size_t)4 * EMB * EMB;

    dim3 blk(256);
    // q|u = acts(x [Wq;Wu]^T) -> (b,h,l,hd) pair
    gemm_kernel<3><<<dim3(16, 128), blk, 0, stream>>>(x16, Wqu, qb, MROWS, 2 * EMB, EMB);
    // kT|vT = acts([Wk;Wv] x^T) -> (b,h,hd,l) pair
    gemm_kernel<4><<<dim3(128, 16), blk, 0, stream>>>(Wkv, x16, kTb, 2 * EMB, MROWS, EMB);

    // retention core
    kv_split_kernel<<<dim3(BH, KVSPLIT), blk, 0, stream>>>(kTb, vTb, kv32);
    ret_out_kernel<<<dim3(BH, 8), blk, 0, stream>>>(qb, ub, kv32, ob);

    // final: out = o @ Wo^T, fp32
    gemm_kernel<0><<<dim3(8, 128), blk, 0, stream>>>(ob, Wo, d_out, MROWS, EMB, EMB);
}

// Round 4
// 449.303 us; speedup vs baseline: 1.8696x; 1.0009x over previous
//
#include <hip/hip_runtime.h>

typedef _Float16 f16;
typedef _Float16 f16x4 __attribute__((ext_vector_type(4)));
typedef _Float16 f16x8 __attribute__((ext_vector_type(8)));
typedef float f32x4 __attribute__((ext_vector_type(4)));

#define EMB 1024
#define SEQL 4096
#define BATCH 4
#define NH 16
#define HD 64
#define BH 64           // BATCH*NH
#define MROWS 16384     // BATCH*SEQL
#define KVSPLIT 16      // l-chunks for split-K kv

#define GLOAD_LDS(gp, lp) \
    __builtin_amdgcn_global_load_lds((const __attribute__((address_space(1))) void*)(gp), \
                                     (__attribute__((address_space(3))) void*)(lp), 16, 0, 0)

// ---------------- fp32 -> fp16 convert ----------------
__global__ void cvt_kernel(const float* __restrict__ in, f16* __restrict__ out, int n4) {
    int i = blockIdx.x * blockDim.x + threadIdx.x;
    if (i < n4) {
        float4 v = ((const float4*)in)[i];
        f16x4 o = { (f16)v.x, (f16)v.y, (f16)v.z, (f16)v.w };
        ((f16x4*)out)[i] = o;
    }
}

struct WPtrs { const float* p[5]; };

// five 1024x1024 weights in one launch; dst contiguous in ws (order given by wp)
__global__ void cvt_w_kernel(WPtrs wp, f16* __restrict__ out) {
    int i = blockIdx.x * blockDim.x + threadIdx.x;
    int wsel = blockIdx.y;
    const float4* src = (const float4*)wp.p[wsel];
    float4 v = src[i];
    f16x4 o = { (f16)v.x, (f16)v.y, (f16)v.z, (f16)v.w };
    ((f16x4*)(out + (size_t)wsel * EMB * EMB))[i] = o;
}

__global__ void zero_kernel(float4* __restrict__ p, int n4) {
    int i = blockIdx.x * blockDim.x + threadIdx.x;
    if (i < n4) p[i] = float4{0.f, 0.f, 0.f, 0.f};
}

// ---------------- m97-style MFMA GEMM: C[m][n] = act( sum_k A[m][k]*Bt[n][k] ) ----------------
// 128x128 block tile, BK=32, LDS staging via global_load_lds width-16 with XOR chunk swizzle
// (row r chunk c stored at position c ^ ((r>>1)&3) -> 2-way banks = free), 4 waves x 64x64.
// MFMA operands swapped (bf first) so each lane holds 4 consecutive n-cols per acc reg ->
// vectorized epilogue stores (f16x4 / float4).
// MODE 0: fp32 out, plain row-major (row*N+col)                     [final Wo GEMM]
// MODE 3: f16 out, merged q|u: col<1024 -> relu/8 into q (b,h,l,hd); col>=1024 -> silu into u
// MODE 4: f16 out, merged kT|vT: row<1024 -> relu/8 into kT (b,h,hd,l); row>=1024 -> vT plain
template<int MODE>
__global__ __launch_bounds__(256) void gemm_kernel(
    const f16* __restrict__ A, const f16* __restrict__ Bt,
    void* __restrict__ Cv, int M, int N, int K)
{
    __shared__ f16 As[128 * 32];
    __shared__ f16 Bs[128 * 32];

    const int lane = threadIdx.x & 63;
    const int w    = threadIdx.x >> 6;
    const int rw   = lane & 15;
    const int quad = lane >> 4;
    const int m0 = blockIdx.y * 128;
    const int n0 = blockIdx.x * 128;
    const int mw = (w >> 1) * 64;
    const int nw = (w & 1) * 64;

    // staging: lane i -> row srow=i>>2, physical chunk p=i&3 holds global chunk p^((srow>>1)&3)
    const int srow = lane >> 2;
    const int scol = (((lane & 3) ^ ((lane >> 3) & 3)) * 8);
    const f16* ag0 = A  + (size_t)(m0 + w * 16 + srow) * K + scol;
    const f16* ag1 = A  + (size_t)(m0 + 64 + w * 16 + srow) * K + scol;
    const f16* bg0 = Bt + (size_t)(n0 + w * 16 + srow) * K + scol;
    const f16* bg1 = Bt + (size_t)(n0 + 64 + w * 16 + srow) * K + scol;
    f16* la0 = &As[(w * 16) * 32];
    f16* la1 = &As[(64 + w * 16) * 32];
    f16* lb0 = &Bs[(w * 16) * 32];
    f16* lb1 = &Bs[(64 + w * 16) * 32];

    // fragment read: logical chunk quad of row r is at position quad ^ ((r>>1)&3);
    // rows differ from rw by multiples of 16, so swz depends only on rw
    const int swz = (quad ^ ((rw >> 1) & 3)) * 8;

    f32x4 acc[4][4] = {};

    for (int k0 = 0; k0 < K; k0 += 32) {
        __syncthreads();
        GLOAD_LDS(ag0 + k0, la0);
        GLOAD_LDS(ag1 + k0, la1);
        GLOAD_LDS(bg0 + k0, lb0);
        GLOAD_LDS(bg1 + k0, lb1);
        __syncthreads();

        f16x8 af[4], bf[4];
        #pragma unroll
        for (int i = 0; i < 4; i++)
            af[i] = *(const f16x8*)&As[(mw + 16 * i + rw) * 32 + swz];
        #pragma unroll
        for (int j = 0; j < 4; j++)
            bf[j] = *(const f16x8*)&Bs[(nw + 16 * j + rw) * 32 + swz];
        #pragma unroll
        for (int i = 0; i < 4; i++)
            #pragma unroll
            for (int j = 0; j < 4; j++)
                acc[i][j] = __builtin_amdgcn_mfma_f32_16x16x32_f16(bf[j], af[i], acc[i][j], 0, 0, 0);
    }

    // swapped-operand C layout: lane -> m = ...+rw ; regs r -> 4 consecutive n = ...+quad*4+r
    #pragma unroll
    for (int i = 0; i < 4; i++) {
        #pragma unroll
        for (int j = 0; j < 4; j++) {
            const int m_idx = m0 + mw + 16 * i + rw;
            const int n_idx = n0 + nw + 16 * j + quad * 4;
            if (MODE == 0) {
                float4 vv = { acc[i][j][0], acc[i][j][1], acc[i][j][2], acc[i][j][3] };
                *(float4*)&((float*)Cv)[(size_t)m_idx * N + n_idx] = vv;
            } else if (MODE == 3) {
                int sel = n_idx >> 10, e = n_idx & 1023;
                int b = m_idx >> 12, l = m_idx & 4095, h = e >> 6, hd = e & 63;
                f16x4 o;
                #pragma unroll
                for (int r = 0; r < 4; r++) {
                    float v = acc[i][j][r];
                    o[r] = (f16)(sel ? (v / (1.0f + __expf(-v))) : (fmaxf(v, 0.0f) * 0.125f));
                }
                *(f16x4*)&((f16*)Cv)[(size_t)sel * MROWS * EMB +
                                     (((size_t)(b * 16 + h) * 4096 + l) << 6) + hd] = o;
            } else {
                int sel = m_idx >> 10, e = m_idx & 1023;
                int b = n_idx >> 12, l = n_idx & 4095;
                f16x4 o;
                #pragma unroll
                for (int r = 0; r < 4; r++) {
                    float v = acc[i][j][r];
                    o[r] = (f16)(sel ? v : (fmaxf(v, 0.0f) * 0.125f));
                }
                *(f16x4*)&((f16*)Cv)[(size_t)sel * MROWS * EMB +
                                     (((size_t)b * 1024 + e) << 12) + l] = o;
            }
        }
    }
}

// ---------------- split-K kv: kv[m][n] += sum_{l in chunk} k[l][m]*v[l][n] ----------------
__global__ __launch_bounds__(256) void kv_split_kernel(
    const f16* __restrict__ kT, const f16* __restrict__ vT, float* __restrict__ kv32)
{
    const int bh    = blockIdx.x;
    const int chunk = blockIdx.y;
    const int lane  = threadIdx.x & 63;
    const int w     = threadIdx.x >> 6;
    const int rw    = lane & 15;
    const int quad  = lane >> 4;
    const int lbase = chunk * (SEQL / KVSPLIT);

    const f16* kp = kT + (size_t)bh * HD * SEQL + (size_t)(w * 16 + rw) * SEQL + lbase + quad * 8;
    const f16* vp = vT + (size_t)bh * HD * SEQL + (size_t)rw * SEQL + lbase + quad * 8;

    f32x4 acc[4] = {};
    for (int k0 = 0; k0 < SEQL / KVSPLIT; k0 += 32) {
        f16x8 a = *(const f16x8*)(kp + k0);
        #pragma unroll
        for (int t = 0; t < 4; t++) {
            f16x8 b = *(const f16x8*)(vp + (size_t)16 * t * SEQL + k0);
            acc[t] = __builtin_amdgcn_mfma_f32_16x16x32_f16(a, b, acc[t], 0, 0, 0);
        }
    }
    float* out = kv32 + (size_t)bh * HD * HD;
    #pragma unroll
    for (int t = 0; t < 4; t++)
        #pragma unroll
        for (int r = 0; r < 4; r++)
            atomicAdd(&out[(w * 16 + quad * 4 + r) * 64 + t * 16 + rw], acc[t][r]);
}

// ---------------- out = SRMSNorm(q @ kv) * u, written to (b,l,emb) f16 ----------------
__global__ __launch_bounds__(256) void ret_out_kernel(
    const f16* __restrict__ q, const f16* __restrict__ u,
    const float* __restrict__ kv32, f16* __restrict__ o)
{
    const int bh    = blockIdx.x;
    const int chunk = blockIdx.y;
    const int lane  = threadIdx.x & 63;
    const int w     = threadIdx.x >> 6;
    const int rw    = lane & 15;
    const int quad  = lane >> 4;

    // kv fragments (loop-invariant): B[k][n] with k = s*32+quad*8+j, n = t*16+rw
    const float* kvp = kv32 + (size_t)bh * 4096;
    f16x8 bf[2][4];
    #pragma unroll
    for (int s = 0; s < 2; s++)
        #pragma unroll
        for (int t = 0; t < 4; t++)
            #pragma unroll
            for (int j = 0; j < 8; j++)
                bf[s][t][j] = (f16)kvp[(s * 32 + quad * 8 + j) * 64 + t * 16 + rw];

    const f16* qp = q + (size_t)bh * SEQL * HD;
    const f16* up = u + (size_t)bh * SEQL * HD;
    const int b = bh >> 4, h = bh & 15;
    f16* op = o + (size_t)b * SEQL * EMB + h * 64;

    const int l_wave = chunk * 512 + w * 128;
    for (int s = 0; s < 8; s++) {
        const int l0 = l_wave + s * 16;
        f16x8 a0 = *(const f16x8*)(qp + (size_t)(l0 + rw) * 64 + quad * 8);
        f16x8 a1 = *(const f16x8*)(qp + (size_t)(l0 + rw) * 64 + 32 + quad * 8);
        f32x4 acc[4] = {};
        #pragma unroll
        for (int t = 0; t < 4; t++) {
            acc[t] = __builtin_amdgcn_mfma_f32_16x16x32_f16(a0, bf[0][t], acc[t], 0, 0, 0);
            acc[t] = __builtin_amdgcn_mfma_f32_16x16x32_f16(a1, bf[1][t], acc[t], 0, 0, 0);
        }
        float inv[4];
        #pragma unroll
        for (int r = 0; r < 4; r++) {
            float ss = acc[0][r] * acc[0][r] + acc[1][r] * acc[1][r]
                     + acc[2][r] * acc[2][r] + acc[3][r] * acc[3][r];
            #pragma unroll
            for (int msk = 1; msk < 16; msk <<= 1)
                ss += __shfl_xor(ss, msk, 16);
            inv[r] = 8.0f / fmaxf(sqrtf(ss), 8e-12f);
        }
        #pragma unroll
        for (int t = 0; t < 4; t++)
            #pragma unroll
            for (int r = 0; r < 4; r++) {
                int l = l0 + quad * 4 + r;
                int col = t * 16 + rw;
                float uval = (float)up[(size_t)l * 64 + col];
                op[(size_t)l * EMB + col] = (f16)(acc[t][r] * inv[r] * uval);
            }
    }
}

extern "C" void kernel_launch(void* const* d_in, const int* in_sizes, int n_in,
                              void* d_out, int out_size, void* d_ws, size_t ws_size,
                              hipStream_t stream)
{
    const float* x = (const float*)d_in[0];
    // dst slot order: Wq, Wu, Wk, Wv, Wo  (so [Wq;Wu] and [Wk;Wv] are contiguous)
    WPtrs wp;
    wp.p[0] = (const float*)d_in[1];  // Wq
    wp.p[1] = (const float*)d_in[4];  // Wu
    wp.p[2] = (const float*)d_in[2];  // Wk
    wp.p[3] = (const float*)d_in[3];  // Wv
    wp.p[4] = (const float*)d_in[5];  // Wo

    char* ws = (char*)d_ws;
    size_t off = 0;
    f16* x16 = (f16*)(ws + off); off += (size_t)MROWS * EMB * 2;
    f16* w16 = (f16*)(ws + off); off += (size_t)5 * EMB * EMB * 2;
    f16* qb  = (f16*)(ws + off); off += (size_t)MROWS * EMB * 2;   // q
    f16* ub  = (f16*)(ws + off); off += (size_t)MROWS * EMB * 2;   // u (contiguous after q)
    f16* kTb = (f16*)(ws + off); off += (size_t)MROWS * EMB * 2;   // kT
    f16* vTb = (f16*)(ws + off); off += (size_t)MROWS * EMB * 2;   // vT (contiguous after kT)
    float* kv32 = (float*)(ws + off); off += (size_t)BH * HD * HD * 4;
    f16* ob  = x16;  // reuse: x16 dead after the two merged projection GEMMs
    (void)ub; (void)vTb;

    // converts + kv zero-init
    cvt_kernel<<<(MROWS * EMB / 4) / 256, 256, 0, stream>>>(x, x16, MROWS * EMB / 4);
    cvt_w_kernel<<<dim3((EMB * EMB / 4) / 256, 5), 256, 0, stream>>>(wp, w16);
    zero_kernel<<<(BH * HD * HD / 4 + 255) / 256, 256, 0, stream>>>((float4*)kv32, BH * HD * HD / 4);

    f16* Wqu = w16;                              // [Wq; Wu]  2048 x 1024
    f16* Wkv = w16 + (size_t)2 * EMB * EMB;      // [Wk; Wv]  2048 x 1024
    f16* Wo  = w16 + (size_t)4 * EMB * EMB;

    dim3 blk(256);
    // q|u = acts(x [Wq;Wu]^T) -> (b,h,l,hd) pair
    gemm_kernel<3><<<dim3(16, 128), blk, 0, stream>>>(x16, Wqu, qb, MROWS, 2 * EMB, EMB);
    // kT|vT = acts([Wk;Wv] x^T) -> (b,h,hd,l) pair
    gemm_kernel<4><<<dim3(128, 16), blk, 0, stream>>>(Wkv, x16, kTb, 2 * EMB, MROWS, EMB);

    // retention core
    kv_split_kernel<<<dim3(BH, KVSPLIT), blk, 0, stream>>>(kTb, vTb, kv32);
    ret_out_kernel<<<dim3(BH, 8), blk, 0, stream>>>(qb, ub, kv32, ob);

    // final: out = o @ Wo^T, fp32
    gemm_kernel<0><<<dim3(8, 128), blk, 0, stream>>>(ob, Wo, d_out, MROWS, EMB, EMB);
}